// Round 3
// baseline (928.756 us; speedup 1.0000x reference)
//
#include <hip/hip_runtime.h>
#include <hip/hip_bf16.h>

// Problem constants
#define BATCH 32
#define C 160
#define H 112
#define W 112
#define HW (H * W)            // 12544
#define NT 7                  // N-tiles per row: 7*16 = 112
#define HP (H / 2)            // 56 row-pairs

typedef __bf16 bf16_t;
typedef bf16_t bf16x8 __attribute__((ext_vector_type(8)));
typedef float f32x4 __attribute__((ext_vector_type(4)));

// Workspace layout (bytes).
// h is gelu(bn(x)) in [b][y][x][c] bf16 (c fastest) so stage-F B-fragments and
// all four spatial shifts are single aligned dwordx4 loads.
// wtap holds the 5 COMPOSED matrices M_kb = W_fuse[:,32kb:32kb+32] @ W_kb
// (160x160 each) packed in MFMA A-fragment order, kb interleaved innermost:
//   idx = (((mt*5 + ks)*5 + kb)*64 + lane)*8 + j
//   row m = mt*16 + (lane&15), col k = ks*32 + (lane>>4)*8 + j
#define H_BYTES   ((size_t)BATCH * HW * C * 2)   // 128,450,560
#define WTAP_OFF  (H_BYTES)
#define WTAP_B    (5 * C * C * 2)                // 256,000
#define BTOT_OFF  (WTAP_OFF + WTAP_B)            // 160 f32 (b_fuse + sum of folded branch biases)
#define BIASK_OFF (BTOT_OFF + 640)               // 5 x 160 f32 folded per-tap biases
#define BN2_OFF   (BIASK_OFF + 3200)             // float2 {scale, shift} per channel

// Exact GELU via branchless A&S-7.1.26 erf (|err|<=1.5e-7 << bf16 quantum).
__device__ __forceinline__ float gelu_exact(float h) {
    float u  = h * 0.70710678118654752f;
    float au = __builtin_fabsf(u);
    float tt = __builtin_amdgcn_rcpf(__builtin_fmaf(0.3275911f, au, 1.0f));
    float poly = tt * __builtin_fmaf(tt,
                      __builtin_fmaf(tt,
                      __builtin_fmaf(tt,
                      __builtin_fmaf(tt, 1.061405429f, -1.453152027f),
                                         1.421413741f),
                                        -0.284496736f),
                                         0.254829592f);
    float e  = __builtin_amdgcn_exp2f(-au * au * 1.4426950408889634f);
    float er = __builtin_fmaf(-poly, e, 1.0f);
    er = __builtin_copysignf(er, u);
    return 0.5f * h * (1.0f + er);
}

// ---------------------------------------------------------------------------
// Prep: bn scale/shift; composed matrices M_kb = W_fuse_kb @ W_kb packed into
// A-fragment order; folded biases biask[kb] = W_fuse_kb @ b_kb and
// btot = b_fuse + sum_kb biask[kb].
// ---------------------------------------------------------------------------
__global__ __launch_bounds__(256) void prep_kernel(
    const float* __restrict__ Wt, const float* __restrict__ Wb,
    const float* __restrict__ Wr, const float* __restrict__ Wl,
    const float* __restrict__ Wc,
    const float* __restrict__ bt, const float* __restrict__ bb,
    const float* __restrict__ br, const float* __restrict__ bl,
    const float* __restrict__ bc,
    const float* __restrict__ Wfuse, const float* __restrict__ bfuse,
    const float* __restrict__ gamma, const float* __restrict__ beta,
    const float* __restrict__ mean, const float* __restrict__ var,
    char* __restrict__ ws)
{
    bf16_t* wtapf = (bf16_t*)(ws + WTAP_OFF);
    float*  btot  = (float*)(ws + BTOT_OFF);
    float*  biask = (float*)(ws + BIASK_OFF);
    float2* bn2   = (float2*)(ws + BN2_OFF);

    const float* Wbr[5] = {Wt, Wb, Wr, Wl, Wc};
    const float* bbr[5] = {bt, bb, br, bl, bc};

    int tid = blockIdx.x * blockDim.x + threadIdx.x;
    int nth = gridDim.x * blockDim.x;

    // Composed A-fragments: 5*10*5*64*8 = 128000 entries, 32-term dot each.
    for (int idx = tid; idx < 5 * 10 * 5 * 64 * 8; idx += nth) {
        int j    = idx & 7;
        int lane = (idx >> 3) & 63;
        int rest = idx >> 9;
        int kb   = rest % 5;
        int tmp  = rest / 5;
        int ks   = tmp % 5;
        int mt   = tmp / 5;
        int m = mt * 16 + (lane & 15);
        int k = ks * 32 + (lane >> 4) * 8 + j;
        float s = 0.0f;
        const float* wf = Wfuse + m * C + kb * 32;
        const float* wb2 = Wbr[kb];
#pragma unroll 8
        for (int o = 0; o < 32; ++o)
            s = __builtin_fmaf(wf[o], wb2[o * C + k], s);
        wtapf[idx] = (bf16_t)s;
    }
    // Folded biases + bn params.
    for (int c = tid; c < C; c += nth) {
        float tot = bfuse[c];
        for (int kb = 0; kb < 5; ++kb) {
            float s = 0.0f;
            const float* wf = Wfuse + c * C + kb * 32;
            for (int o = 0; o < 32; ++o)
                s = __builtin_fmaf(wf[o], bbr[kb][o], s);
            biask[kb * C + c] = s;
            tot += s;
        }
        btot[c] = tot;
        float sc = gamma[c] * rsqrtf(var[c] + 1e-5f);
        bn2[c] = make_float2(sc, beta[c] - mean[c] * sc);
    }
}

// ---------------------------------------------------------------------------
// Stage H: h[b][y][x][c] = bf16(gelu(bn(x))). Pure elementwise transpose.
// Thread = (b, c32-block, y, 2-px): 32 float2 loads (fully coalesced, 32
// outstanding per thread), 64 gelu, 8 dwordx4 stores completing full 64B
// sectors ([px][c] with 64B per (px, c32-block)).
// ---------------------------------------------------------------------------
__global__ __launch_bounds__(256) void stageh_kernel(
    const float* __restrict__ x, char* __restrict__ ws)
{
    const float2* __restrict__ bn2 = (const float2*)(ws + BN2_OFF);
    bf16_t* __restrict__ h = (bf16_t*)ws;

    int tid = blockIdx.x * 256 + threadIdx.x;
    int x2  = tid % 56;
    int y   = (tid / 56) % H;
    int c32 = (tid / (56 * H)) % 5;
    int b   = tid / (56 * H * 5);
    int px  = x2 * 2;

    const float* xp = x + ((size_t)b * C + c32 * 32) * HW + y * W + px;

    float2 v[32];
#pragma unroll
    for (int j = 0; j < 32; ++j)
        v[j] = *(const float2*)(xp + (size_t)j * HW);

    bf16x8 o0[4], o1[4];
#pragma unroll
    for (int j = 0; j < 32; ++j) {
        float2 sb = bn2[c32 * 32 + j];
        o0[j >> 3][j & 7] = (bf16_t)gelu_exact(__builtin_fmaf(v[j].x, sb.x, sb.y));
        o1[j >> 3][j & 7] = (bf16_t)gelu_exact(__builtin_fmaf(v[j].y, sb.x, sb.y));
    }

    bf16_t* hp = h + ((size_t)b * HW + (size_t)y * W + px) * C + c32 * 32;
#pragma unroll
    for (int k = 0; k < 4; ++k) {
        *(bf16x8*)(hp + k * 8) = o0[k];
        *(bf16x8*)(hp + C + k * 8) = o1[k];
    }
}

// ---------------------------------------------------------------------------
// Stage F: out(y,x) = sum_kb M_kb @ h(shift_kb(y,x)) + btot, with border
// corrections. One wave per (b, row-pair, 16-px tile). Per ks: 8 unique
// h-fragments (4 straight rows y0-1..y1+1, 4 x-shifted) as dwordx4 loads with
// clamped addresses + in-register zero masking; 50 A-loads, 100 MFMA.
// Tap->frag: t:(S2,S3) b:(S0,S1) r:(L0,L1) l:(R0,R1) c:(S1,S2).
// ---------------------------------------------------------------------------
__global__ __launch_bounds__(256, 2) void stagef_kernel(
    char* __restrict__ ws, float* __restrict__ out)
{
    const bf16_t* __restrict__ h = (const bf16_t*)ws;
    const bf16_t* __restrict__ wtapf = (const bf16_t*)(ws + WTAP_OFF);
    const float*  __restrict__ btot  = (const float*)(ws + BTOT_OFF);
    const float*  __restrict__ biask = (const float*)(ws + BIASK_OFF);

    int wid  = blockIdx.x * 4 + (threadIdx.x >> 6);
    int lane = threadIdx.x & 63;
    int b   = wid / (HP * NT);
    int rem = wid - b * (HP * NT);
    int yp  = rem / NT;
    int t   = rem - yp * NT;
    int y0  = yp * 2, y1 = y0 + 1;
    int nl = lane & 15, quad = lane >> 4;
    int px = t * 16 + nl;

    bool m_up = (y0 == 0);
    bool m_dn = (y1 == H - 1);
    bool m_l  = (px == 0);
    bool m_r  = (px == W - 1);
    int ym  = m_up ? 0 : y0 - 1;     // clamped (safe) addresses
    int ypl = m_dn ? y1 : y1 + 1;
    int pxl = m_l ? px : px - 1;
    int pxr = m_r ? px : px + 1;

    const bf16_t* hb = h + (size_t)b * HW * C;

    f32x4 acc0[10], acc1[10];
#pragma unroll
    for (int mt = 0; mt < 10; ++mt) {
        f32x4 bias = *(const f32x4*)&btot[mt * 16 + quad * 4];
        acc0[mt] = bias;
        acc1[mt] = bias;
    }

    bf16x8 zero;
#pragma unroll
    for (int j = 0; j < 8; ++j) zero[j] = (bf16_t)0.0f;

#pragma unroll
    for (int ks = 0; ks < 5; ++ks) {
        int co = ks * 32 + quad * 8;
        auto ldh = [&](int yy, int xx) -> bf16x8 {
            return *(const bf16x8*)&hb[((size_t)yy * W + xx) * C + co];
        };
        bf16x8 S0 = ldh(ym, px);
        bf16x8 S1 = ldh(y0, px);
        bf16x8 S2 = ldh(y1, px);
        bf16x8 S3 = ldh(ypl, px);
        bf16x8 L0 = ldh(y0, pxl);
        bf16x8 L1 = ldh(y1, pxl);
        bf16x8 R0 = ldh(y0, pxr);
        bf16x8 R1 = ldh(y1, pxr);
        if (m_up) S0 = zero;
        if (m_dn) S3 = zero;
        if (m_l) { L0 = zero; L1 = zero; }
        if (m_r) { R0 = zero; R1 = zero; }

#pragma unroll
        for (int mt = 0; mt < 10; ++mt) {
            const bf16_t* wp = &wtapf[(size_t)(((mt * 5 + ks) * 5) * 64 + lane) * 8];
            bf16x8 a_t = *(const bf16x8*)(wp + 0 * 512);
            bf16x8 a_b = *(const bf16x8*)(wp + 1 * 512);
            bf16x8 a_r = *(const bf16x8*)(wp + 2 * 512);
            bf16x8 a_l = *(const bf16x8*)(wp + 3 * 512);
            bf16x8 a_c = *(const bf16x8*)(wp + 4 * 512);
            acc0[mt] = __builtin_amdgcn_mfma_f32_16x16x32_bf16(a_t, S2, acc0[mt], 0, 0, 0);
            acc1[mt] = __builtin_amdgcn_mfma_f32_16x16x32_bf16(a_t, S3, acc1[mt], 0, 0, 0);
            acc0[mt] = __builtin_amdgcn_mfma_f32_16x16x32_bf16(a_b, S0, acc0[mt], 0, 0, 0);
            acc1[mt] = __builtin_amdgcn_mfma_f32_16x16x32_bf16(a_b, S1, acc1[mt], 0, 0, 0);
            acc0[mt] = __builtin_amdgcn_mfma_f32_16x16x32_bf16(a_r, L0, acc0[mt], 0, 0, 0);
            acc1[mt] = __builtin_amdgcn_mfma_f32_16x16x32_bf16(a_r, L1, acc1[mt], 0, 0, 0);
            acc0[mt] = __builtin_amdgcn_mfma_f32_16x16x32_bf16(a_l, R0, acc0[mt], 0, 0, 0);
            acc1[mt] = __builtin_amdgcn_mfma_f32_16x16x32_bf16(a_l, R1, acc1[mt], 0, 0, 0);
            acc0[mt] = __builtin_amdgcn_mfma_f32_16x16x32_bf16(a_c, S1, acc0[mt], 0, 0, 0);
            acc1[mt] = __builtin_amdgcn_mfma_f32_16x16x32_bf16(a_c, S2, acc1[mt], 0, 0, 0);
        }
    }

    // Border bias corrections: invalid tap contributes neither matmul (zeroed
    // frag) nor its folded bias (subtract from the btot-initialized acc).
    if (y0 == 0) {
#pragma unroll
        for (int mt = 0; mt < 10; ++mt)
            acc0[mt] -= *(const f32x4*)&biask[1 * C + mt * 16 + quad * 4];  // b-tap
    }
    if (y1 == H - 1) {
#pragma unroll
        for (int mt = 0; mt < 10; ++mt)
            acc1[mt] -= *(const f32x4*)&biask[0 * C + mt * 16 + quad * 4];  // t-tap
    }
    if (m_l) {
#pragma unroll
        for (int mt = 0; mt < 10; ++mt) {
            f32x4 c2 = *(const f32x4*)&biask[2 * C + mt * 16 + quad * 4];   // r-tap
            acc0[mt] -= c2; acc1[mt] -= c2;
        }
    }
    if (m_r) {
#pragma unroll
        for (int mt = 0; mt < 10; ++mt) {
            f32x4 c2 = *(const f32x4*)&biask[3 * C + mt * 16 + quad * 4];   // l-tap
            acc0[mt] -= c2; acc1[mt] -= c2;
        }
    }

    size_t ob = (size_t)b * C * HW + (size_t)y0 * W + px;
#pragma unroll
    for (int mt = 0; mt < 10; ++mt) {
#pragma unroll
        for (int r = 0; r < 4; ++r) {
            int m = mt * 16 + quad * 4 + r;
            out[ob + (size_t)m * HW] = acc0[mt][r];
            out[ob + (size_t)m * HW + W] = acc1[mt][r];
        }
    }
}

// ---------------------------------------------------------------------------
extern "C" void kernel_launch(void* const* d_in, const int* in_sizes, int n_in,
                              void* d_out, int out_size, void* d_ws, size_t ws_size,
                              hipStream_t stream)
{
    const float* x     = (const float*)d_in[0];
    const float* gamma = (const float*)d_in[1];
    const float* beta  = (const float*)d_in[2];
    const float* mean  = (const float*)d_in[3];
    const float* var   = (const float*)d_in[4];
    const float* Wt    = (const float*)d_in[5];
    const float* bt    = (const float*)d_in[6];
    const float* Wb    = (const float*)d_in[7];
    const float* bb    = (const float*)d_in[8];
    const float* Wr    = (const float*)d_in[9];
    const float* br    = (const float*)d_in[10];
    const float* Wl    = (const float*)d_in[11];
    const float* bl    = (const float*)d_in[12];
    const float* Wc    = (const float*)d_in[13];
    const float* bc    = (const float*)d_in[14];
    const float* Wfuse = (const float*)d_in[15];
    const float* bfuse = (const float*)d_in[16];

    char* ws = (char*)d_ws;
    float* out = (float*)d_out;

    prep_kernel<<<160, 256, 0, stream>>>(Wt, Wb, Wr, Wl, Wc, bt, bb, br, bl, bc,
                                         Wfuse, bfuse, gamma, beta, mean, var, ws);

    int nh = (BATCH * 5 * H * 56) / 256;   // 1,003,520 threads / 256
    stageh_kernel<<<nh, 256, 0, stream>>>(x, ws);

    int nf = (BATCH * HP * NT) / 4;        // 12544 waves / 4 per block
    stagef_kernel<<<nf, 256, 0, stream>>>(ws, out);
}

// Round 4
// 689.577 us; speedup vs baseline: 1.3468x; 1.3468x over previous
//
#include <hip/hip_runtime.h>
#include <hip/hip_bf16.h>

// Problem constants
#define BATCH 32
#define C 160
#define H 112
#define W 112
#define HW (H * W)            // 12544
#define NT 7                  // N-tiles per row: 7*16 = 112
#define HP (H / 2)            // 56 row-pairs

typedef __bf16 bf16_t;
typedef bf16_t bf16x8 __attribute__((ext_vector_type(8)));
typedef float f32x4 __attribute__((ext_vector_type(4)));
typedef unsigned int ui32x4 __attribute__((ext_vector_type(4)));

// Workspace layout (bytes).
// h is gelu(bn(x)) in [b][y][x][c] bf16 (c fastest) so stage-F B-fragments and
// all four spatial shifts are single aligned dwordx4 loads.
// wtap holds the 5 COMPOSED matrices M_kb = W_fuse[:,32kb:32kb+32] @ W_kb
// (160x160 each) packed in MFMA A-fragment order, reordered for stage-F's
// LDS staging: slice s = ks (5 slices), padded to 3328 16B-units each:
//   elem idx = ks*26624 + (((mt*5 + kb)*64 + lane)*8 + j)
//   row m = mt*16 + (lane&15), col k = ks*32 + (lane>>4)*8 + j
#define H_BYTES    ((size_t)BATCH * HW * C * 2)  // 128,450,560
#define WTAP_OFF   (H_BYTES)
#define SLICE_EL   26624                          // padded elems per ks-slice (3328*8)
#define SLICE_EL_R 25600                          // real elems per ks-slice
#define WTAP_B     (5 * SLICE_EL * 2)             // 266,240
#define BTOT_OFF   (WTAP_OFF + WTAP_B)            // 160 f32 (b_fuse + folded biases)
#define BIASK_OFF  (BTOT_OFF + 640)               // 5 x 160 f32 folded per-tap biases
#define BN2_OFF    (BIASK_OFF + 3200)             // float2 {scale, shift} per channel

// Exact GELU via branchless A&S-7.1.26 erf (|err|<=1.5e-7 << bf16 quantum).
__device__ __forceinline__ float gelu_exact(float h) {
    float u  = h * 0.70710678118654752f;
    float au = __builtin_fabsf(u);
    float tt = __builtin_amdgcn_rcpf(__builtin_fmaf(0.3275911f, au, 1.0f));
    float poly = tt * __builtin_fmaf(tt,
                      __builtin_fmaf(tt,
                      __builtin_fmaf(tt,
                      __builtin_fmaf(tt, 1.061405429f, -1.453152027f),
                                         1.421413741f),
                                        -0.284496736f),
                                         0.254829592f);
    float e  = __builtin_amdgcn_exp2f(-au * au * 1.4426950408889634f);
    float er = __builtin_fmaf(-poly, e, 1.0f);
    er = __builtin_copysignf(er, u);
    return 0.5f * h * (1.0f + er);
}

// ---------------------------------------------------------------------------
// Prep: bn scale/shift; composed matrices M_kb = W_fuse_kb @ W_kb packed into
// A-fragment order (ks-slice-major, padded); folded biases.
// ---------------------------------------------------------------------------
__global__ __launch_bounds__(256) void prep_kernel(
    const float* __restrict__ Wt, const float* __restrict__ Wb,
    const float* __restrict__ Wr, const float* __restrict__ Wl,
    const float* __restrict__ Wc,
    const float* __restrict__ bt, const float* __restrict__ bb,
    const float* __restrict__ br, const float* __restrict__ bl,
    const float* __restrict__ bc,
    const float* __restrict__ Wfuse, const float* __restrict__ bfuse,
    const float* __restrict__ gamma, const float* __restrict__ beta,
    const float* __restrict__ mean, const float* __restrict__ var,
    char* __restrict__ ws)
{
    bf16_t* wtapf = (bf16_t*)(ws + WTAP_OFF);
    float*  btot  = (float*)(ws + BTOT_OFF);
    float*  biask = (float*)(ws + BIASK_OFF);
    float2* bn2   = (float2*)(ws + BN2_OFF);

    const float* Wbr[5] = {Wt, Wb, Wr, Wl, Wc};
    const float* bbr[5] = {bt, bb, br, bl, bc};

    int tid = blockIdx.x * blockDim.x + threadIdx.x;
    int nth = gridDim.x * blockDim.x;

    // Composed A-fragments: 5*10*5*64*8 = 128000 real entries, 32-term dot each.
    // New nesting (stage-F consumption order): u = ((((ks*10+mt)*5+kb)*64+lane)*8+j.
    for (int u = tid; u < 128000; u += nth) {
        int j    = u & 7;
        int lane = (u >> 3) & 63;
        int rest = u >> 9;
        int kb   = rest % 5;
        int tmp  = rest / 5;
        int mt   = tmp % 10;
        int ks   = tmp / 10;
        int m = mt * 16 + (lane & 15);
        int k = ks * 32 + (lane >> 4) * 8 + j;
        float s = 0.0f;
        const float* wf = Wfuse + m * C + kb * 32;
        const float* wb2 = Wbr[kb];
#pragma unroll 8
        for (int o = 0; o < 32; ++o)
            s = __builtin_fmaf(wf[o], wb2[o * C + k], s);
        int within = ((mt * 5 + kb) * 64 + lane) * 8 + j;
        wtapf[ks * SLICE_EL + within] = (bf16_t)s;
    }
    // Folded biases + bn params.
    for (int c = tid; c < C; c += nth) {
        float tot = bfuse[c];
        for (int kb = 0; kb < 5; ++kb) {
            float s = 0.0f;
            const float* wf = Wfuse + c * C + kb * 32;
            for (int o = 0; o < 32; ++o)
                s = __builtin_fmaf(wf[o], bbr[kb][o], s);
            biask[kb * C + c] = s;
            tot += s;
        }
        btot[c] = tot;
        float sc = gamma[c] * rsqrtf(var[c] + 1e-5f);
        bn2[c] = make_float2(sc, beta[c] - mean[c] * sc);
    }
}

// ---------------------------------------------------------------------------
// Stage H: h[b][y][x][c] = bf16(gelu(bn(x))). Pure elementwise transpose.
// Thread = (b, c32-block, y, 2-px): 32 float2 loads (fully coalesced, 32
// outstanding per thread), 64 gelu, 8 dwordx4 stores.
// ---------------------------------------------------------------------------
__global__ __launch_bounds__(256) void stageh_kernel(
    const float* __restrict__ x, char* __restrict__ ws)
{
    const float2* __restrict__ bn2 = (const float2*)(ws + BN2_OFF);
    bf16_t* __restrict__ h = (bf16_t*)ws;

    int tid = blockIdx.x * 256 + threadIdx.x;
    int x2  = tid % 56;
    int y   = (tid / 56) % H;
    int c32 = (tid / (56 * H)) % 5;
    int b   = tid / (56 * H * 5);
    int px  = x2 * 2;

    const float* xp = x + ((size_t)b * C + c32 * 32) * HW + y * W + px;

    float2 v[32];
#pragma unroll
    for (int j = 0; j < 32; ++j)
        v[j] = *(const float2*)(xp + (size_t)j * HW);

    bf16x8 o0[4], o1[4];
#pragma unroll
    for (int j = 0; j < 32; ++j) {
        float2 sb = bn2[c32 * 32 + j];
        o0[j >> 3][j & 7] = (bf16_t)gelu_exact(__builtin_fmaf(v[j].x, sb.x, sb.y));
        o1[j >> 3][j & 7] = (bf16_t)gelu_exact(__builtin_fmaf(v[j].y, sb.x, sb.y));
    }

    bf16_t* hp = h + ((size_t)b * HW + (size_t)y * W + px) * C + c32 * 32;
#pragma unroll
    for (int k = 0; k < 4; ++k) {
        *(bf16x8*)(hp + k * 8) = o0[k];
        *(bf16x8*)(hp + C + k * 8) = o1[k];
    }
}

// ---------------------------------------------------------------------------
// Stage F: out(y,x) = sum_kb M_kb @ h(shift_kb(y,x)) + btot.
// v2: composed weights staged per-ks-slice into LDS (52 KB), shared by the
// block's 4 waves -> A-operand reads become conflict-free ds_read_b128 instead
// of 250 per-wave L2 loads (round-3 killer: VGPR=112 allowed ~3 loads in
// flight). Staging: 13 static-index 16B copies per thread, all loads issued
// before any ds_write (no runtime-indexed temp array -> stays in registers).
// Tap->frag: t:(S2,S3) b:(S0,S1) r:(L0,L1) l:(R0,R1) c:(S1,S2).
// ---------------------------------------------------------------------------
__global__ __launch_bounds__(256, 2) void stagef_kernel(
    char* __restrict__ ws, float* __restrict__ out)
{
    const bf16_t* __restrict__ h = (const bf16_t*)ws;
    const bf16_t* __restrict__ wtapf = (const bf16_t*)(ws + WTAP_OFF);
    const float*  __restrict__ btot  = (const float*)(ws + BTOT_OFF);
    const float*  __restrict__ biask = (const float*)(ws + BIASK_OFF);

    __shared__ bf16_t ldsA[SLICE_EL];   // 53,248 B: one padded ks-slice

    int wid  = blockIdx.x * 4 + (threadIdx.x >> 6);
    int lane = threadIdx.x & 63;
    int b   = wid / (HP * NT);
    int rem = wid - b * (HP * NT);
    int yp  = rem / NT;
    int t   = rem - yp * NT;
    int y0  = yp * 2, y1 = y0 + 1;
    int nl = lane & 15, quad = lane >> 4;
    int px = t * 16 + nl;

    bool m_up = (y0 == 0);
    bool m_dn = (y1 == H - 1);
    bool m_l  = (px == 0);
    bool m_r  = (px == W - 1);
    int ym  = m_up ? 0 : y0 - 1;     // clamped (safe) addresses
    int ypl = m_dn ? y1 : y1 + 1;
    int pxl = m_l ? px : px - 1;
    int pxr = m_r ? px : px + 1;

    const bf16_t* hb = h + (size_t)b * HW * C;

    f32x4 acc0[10], acc1[10];
#pragma unroll
    for (int mt = 0; mt < 10; ++mt) {
        f32x4 bias = *(const f32x4*)&btot[mt * 16 + quad * 4];
        acc0[mt] = bias;
        acc1[mt] = bias;
    }

    bf16x8 zero;
#pragma unroll
    for (int j = 0; j < 8; ++j) zero[j] = (bf16_t)0.0f;

#pragma unroll
    for (int ks = 0; ks < 5; ++ks) {
        int co = ks * 32 + quad * 8;
        auto ldh = [&](int yy, int xx) -> bf16x8 {
            return *(const bf16x8*)&hb[((size_t)yy * W + xx) * C + co];
        };
        // Issue the 8 h-fragment loads first (registers) so they overlap the
        // barrier + staging below.
        bf16x8 S0 = ldh(ym, px);
        bf16x8 S1 = ldh(y0, px);
        bf16x8 S2 = ldh(y1, px);
        bf16x8 S3 = ldh(ypl, px);
        bf16x8 L0 = ldh(y0, pxl);
        bf16x8 L1 = ldh(y1, pxl);
        bf16x8 R0 = ldh(y0, pxr);
        bf16x8 R1 = ldh(y1, pxr);
        if (m_up) S0 = zero;
        if (m_dn) S3 = zero;
        if (m_l) { L0 = zero; L1 = zero; }
        if (m_r) { R0 = zero; R1 = zero; }

        // --- stage ks-slice of composed weights into LDS ---
        if (ks) __syncthreads();           // previous slice's readers done
        {
            const ui32x4* src = (const ui32x4*)(wtapf + (size_t)ks * SLICE_EL);
            ui32x4* dst = (ui32x4*)ldsA;
            ui32x4 tmp[13];
#pragma unroll
            for (int i = 0; i < 13; ++i)
                tmp[i] = src[threadIdx.x + i * 256];
#pragma unroll
            for (int i = 0; i < 13; ++i)
                dst[threadIdx.x + i * 256] = tmp[i];
        }
        __syncthreads();                   // slice visible to all waves

        // --- compute: 50 ds_read_b128 + 100 MFMA per wave ---
#pragma unroll
        for (int mt = 0; mt < 10; ++mt) {
            const bf16_t* wp = &ldsA[(size_t)((mt * 5) * 64 + lane) * 8];
            bf16x8 a_t = *(const bf16x8*)(wp + 0 * 512);
            bf16x8 a_b = *(const bf16x8*)(wp + 1 * 512);
            bf16x8 a_r = *(const bf16x8*)(wp + 2 * 512);
            bf16x8 a_l = *(const bf16x8*)(wp + 3 * 512);
            bf16x8 a_c = *(const bf16x8*)(wp + 4 * 512);
            acc0[mt] = __builtin_amdgcn_mfma_f32_16x16x32_bf16(a_t, S2, acc0[mt], 0, 0, 0);
            acc1[mt] = __builtin_amdgcn_mfma_f32_16x16x32_bf16(a_t, S3, acc1[mt], 0, 0, 0);
            acc0[mt] = __builtin_amdgcn_mfma_f32_16x16x32_bf16(a_b, S0, acc0[mt], 0, 0, 0);
            acc1[mt] = __builtin_amdgcn_mfma_f32_16x16x32_bf16(a_b, S1, acc1[mt], 0, 0, 0);
            acc0[mt] = __builtin_amdgcn_mfma_f32_16x16x32_bf16(a_r, L0, acc0[mt], 0, 0, 0);
            acc1[mt] = __builtin_amdgcn_mfma_f32_16x16x32_bf16(a_r, L1, acc1[mt], 0, 0, 0);
            acc0[mt] = __builtin_amdgcn_mfma_f32_16x16x32_bf16(a_l, R0, acc0[mt], 0, 0, 0);
            acc1[mt] = __builtin_amdgcn_mfma_f32_16x16x32_bf16(a_l, R1, acc1[mt], 0, 0, 0);
            acc0[mt] = __builtin_amdgcn_mfma_f32_16x16x32_bf16(a_c, S1, acc0[mt], 0, 0, 0);
            acc1[mt] = __builtin_amdgcn_mfma_f32_16x16x32_bf16(a_c, S2, acc1[mt], 0, 0, 0);
        }
    }

    // Border bias corrections: invalid tap contributes neither matmul (zeroed
    // frag) nor its folded bias (subtract from the btot-initialized acc).
    if (y0 == 0) {
#pragma unroll
        for (int mt = 0; mt < 10; ++mt)
            acc0[mt] -= *(const f32x4*)&biask[1 * C + mt * 16 + quad * 4];  // b-tap
    }
    if (y1 == H - 1) {
#pragma unroll
        for (int mt = 0; mt < 10; ++mt)
            acc1[mt] -= *(const f32x4*)&biask[0 * C + mt * 16 + quad * 4];  // t-tap
    }
    if (m_l) {
#pragma unroll
        for (int mt = 0; mt < 10; ++mt) {
            f32x4 c2 = *(const f32x4*)&biask[2 * C + mt * 16 + quad * 4];   // r-tap
            acc0[mt] -= c2; acc1[mt] -= c2;
        }
    }
    if (m_r) {
#pragma unroll
        for (int mt = 0; mt < 10; ++mt) {
            f32x4 c2 = *(const f32x4*)&biask[3 * C + mt * 16 + quad * 4];   // l-tap
            acc0[mt] -= c2; acc1[mt] -= c2;
        }
    }

    size_t ob = (size_t)b * C * HW + (size_t)y0 * W + px;
#pragma unroll
    for (int mt = 0; mt < 10; ++mt) {
#pragma unroll
        for (int r = 0; r < 4; ++r) {
            int m = mt * 16 + quad * 4 + r;
            out[ob + (size_t)m * HW] = acc0[mt][r];
            out[ob + (size_t)m * HW + W] = acc1[mt][r];
        }
    }
}

// ---------------------------------------------------------------------------
extern "C" void kernel_launch(void* const* d_in, const int* in_sizes, int n_in,
                              void* d_out, int out_size, void* d_ws, size_t ws_size,
                              hipStream_t stream)
{
    const float* x     = (const float*)d_in[0];
    const float* gamma = (const float*)d_in[1];
    const float* beta  = (const float*)d_in[2];
    const float* mean  = (const float*)d_in[3];
    const float* var   = (const float*)d_in[4];
    const float* Wt    = (const float*)d_in[5];
    const float* bt    = (const float*)d_in[6];
    const float* Wb    = (const float*)d_in[7];
    const float* bb    = (const float*)d_in[8];
    const float* Wr    = (const float*)d_in[9];
    const float* br    = (const float*)d_in[10];
    const float* Wl    = (const float*)d_in[11];
    const float* bl    = (const float*)d_in[12];
    const float* Wc    = (const float*)d_in[13];
    const float* bc    = (const float*)d_in[14];
    const float* Wfuse = (const float*)d_in[15];
    const float* bfuse = (const float*)d_in[16];

    char* ws = (char*)d_ws;
    float* out = (float*)d_out;

    prep_kernel<<<160, 256, 0, stream>>>(Wt, Wb, Wr, Wl, Wc, bt, bb, br, bl, bc,
                                         Wfuse, bfuse, gamma, beta, mean, var, ws);

    int nh = (BATCH * 5 * H * 56) / 256;   // 1,003,520 threads / 256
    stageh_kernel<<<nh, 256, 0, stream>>>(x, ws);

    int nf = (BATCH * HP * NT) / 4;        // 12544 waves / 4 per block
    stagef_kernel<<<nf, 256, 0, stream>>>(ws, out);
}